// Round 12
// baseline (248.334 us; speedup 1.0000x reference)
//
#include <hip/hip_runtime.h>

// EquivariantProductBasisBlock (MACE symmetric contraction, corr=3) + o3.Linear
// N=10000 nodes, C=128 channels, L=9 (lmax=2), E=5 elements, fp32 throughout.
//
// R25 changes vs R24 (linear only; contract/table/sort frozen):
//  - R24 confirmed: contract 50.5us (FETCH 102->27MB, VALUBusy 72%). Linear
//    is the co-#1 at 50.5us with VALUBusy 19.7% = pure-FMA floor -> ~80%
//    stall on the per-ci A-load chain (128 dependent VMEM dwords/thread,
//    VGPR=20 -> ~1 load in flight; 8 c1-siblings re-read each A-slice).
//  - Fix: c1-tile 16->32. Per ci: 1 A dword + 2x s_load_dwordx16 + 32 FMA.
//    Total A-load instructions HALVE (4 siblings/slice); latency amortized
//    over 2x work. Grid (40,4,4)=640 blocks=10 waves/CU. acc[32] ~48 VGPR,
//    launch_bounds(256,6) — compile-time indices only (no R18-style spill).
//    All 16 chunk-sibling blocks still on one XCD (strides 40/160 = 0 mod 8).

#define CCH 128
#define LDIM 9
#define NE 5
#define BLK 256
#define TSTR 220             // coeffs per (e,c,dd): 219 + 1 pad (16B-aligned)
#define TGSTR 880            // per (e,c) = 4*TSTR
#define U3LDS 8748           // staged U3 slice (729*12 max)

// -------------------------------------------- sort: count + offs (fused)
__global__ __launch_bounds__(BLK) void count_offs_kernel(
    const float* __restrict__ attrs, int N,
    int* __restrict__ elem, int* __restrict__ gcnt,   // gcnt[5], gcnt[5]=done
    int* __restrict__ offs, int* __restrict__ cur) {
  int n = blockIdx.x * BLK + threadIdx.x;
  int e = 0;
  if (n < N) {
    const float* a = attrs + n * NE;
#pragma unroll
    for (int j = 1; j < NE; ++j)
      if (a[j] > 0.5f) e = j;
    elem[n] = e;
  }
  int lane = threadIdx.x & 63;
#pragma unroll
  for (int k = 0; k < NE; ++k) {
    unsigned long long m = __ballot(n < N && e == k);
    if (m) {
      int leader = __ffsll((long long)m) - 1;
      if (lane == leader) atomicAdd(&gcnt[k], __popcll(m));
    }
  }
  __threadfence();
  __syncthreads();
  if (threadIdx.x == 0) {
    int t = atomicAdd(&gcnt[NE], 1);
    if (t == (int)gridDim.x - 1) {            // last block: prefix sum
      int acc = 0;
      for (int k = 0; k < NE; ++k) {
        int ck = atomicAdd(&gcnt[k], 0);      // coherent read
        offs[k] = acc; cur[k] = acc; acc += ck;
      }
      offs[NE] = acc;
    }
  }
}

// ----------------------------------------------------------- sort: scatter
__global__ __launch_bounds__(BLK) void scatter_kernel(
    const int* __restrict__ elem, int N,
    int* __restrict__ cur, int* __restrict__ order) {
  int n = blockIdx.x * BLK + threadIdx.x;
  if (n >= N) return;
  int e = elem[n];
  int lane = threadIdx.x & 63;
#pragma unroll
  for (int k = 0; k < NE; ++k) {
    if (e == k) {
      unsigned long long m = __ballot(1);
      int cnt = __popcll(m);
      int leader = __ffsll((long long)m) - 1;
      int base = 0;
      if (lane == leader) base = atomicAdd(&cur[k], cnt);
      base = __shfl(base, leader);
      int rank = __popcll(m & ((1ull << lane) - 1ull));
      order[base + rank] = n;
    }
  }
}

// ---- build + FULLY (u,v,w)-symmetrize + pack U(x)w tables (one dd/block)
__global__ __launch_bounds__(BLK) void table_kernel(
    const float* __restrict__ U3_0, const float* __restrict__ U2_0,
    const float* __restrict__ U1_0, const float* __restrict__ U3_1,
    const float* __restrict__ U2_1, const float* __restrict__ U1_1,
    const float* __restrict__ w3_0, const float* __restrict__ w2_0,
    const float* __restrict__ w1_0, const float* __restrict__ w3_1,
    const float* __restrict__ w2_1, const float* __restrict__ w1_1,
    float* __restrict__ table) {
  const int b = blockIdx.x;        // e*CCH + c
  const int dd = blockIdx.y;       // 0..3
  const int e = b / CCH, c = b % CCH;
  float* Tg = table + (size_t)b * TGSTR + dd * TSTR;
  __shared__ float Us[U3LDS];      // raw U3 slice [729*K3]
  __shared__ float U2s[324];       // raw U2 slice [81*K2]
  __shared__ float R3[729];        // rect T3
  __shared__ float R2[81];
  __shared__ float R1l[9];
  __shared__ float w3l[12], w2l[4];
  const int tid = threadIdx.x;
  const int d = dd - 1;
  const int K3 = (dd == 0) ? 10 : 12;
  const int K2 = (dd == 0) ? 3 : 4;

  if (dd == 0) {
    for (int i = tid; i < 7290; i += BLK) Us[i] = U3_0[i];
    for (int i = tid; i < 243; i += BLK)  U2s[i] = U2_0[i];
    if (tid < 10) w3l[tid] = w3_0[(e * 10 + tid) * CCH + c];
    else if (tid < 13) w2l[tid - 10] = w2_0[(e * 3 + (tid - 10)) * CCH + c];
    if (tid < 9) R1l[tid] = U1_0[tid] * w1_0[e * CCH + c];
  } else {
    for (int i = tid; i < 8748; i += BLK) Us[i] = U3_1[d * 8748 + i];
    for (int i = tid; i < 324; i += BLK)  U2s[i] = U2_1[d * 324 + i];
    if (tid < 12) w3l[tid] = w3_1[(e * 12 + tid) * CCH + c];
    else if (tid < 16) w2l[tid - 12] = w2_1[(e * 4 + (tid - 12)) * CCH + c];
    if (tid < 9) R1l[tid] = U1_1[d * 9 + tid] * w1_1[e * CCH + c];
  }
  __syncthreads();
  for (int r = tid; r < 729; r += BLK) {
    float acc = 0.f;
    for (int k = 0; k < K3; ++k) acc += Us[r * K3 + k] * w3l[k];
    R3[r] = acc;
  }
  for (int q = tid; q < 81; q += BLK) {
    float acc = 0.f;
    for (int k = 0; k < K2; ++k) acc += U2s[q * K2 + k] * w2l[k];
    R2[q] = acc;
  }
  __syncthreads();
  // pack: Horner consumption order. Per u: [T1s[u], then per v=u..8:
  //   [T2s[u][v], S3s[u][v][w] for w=v..8]].  Per-u size = (10-u)(11-u)/2.
  for (int i = tid; i < TSTR; i += BLK) {
    float val = 0.f;
    if (i < 219) {
      int rem = i, u = 0;
      while (rem >= (10 - u) * (11 - u) / 2) {
        rem -= (10 - u) * (11 - u) / 2; ++u;
      }
      if (rem == 0) {
        val = R1l[u];
      } else {
        rem -= 1;
        int v = u;
        while (rem >= 10 - v) { rem -= 10 - v; ++v; }
        if (rem == 0) {
          val = (u == v) ? R2[u * 9 + v] : R2[u * 9 + v] + R2[v * 9 + u];
        } else {
          int w = v + (rem - 1);
          if (u == v && v == w)
            val = R3[(u * 9 + u) * 9 + u];
          else if (u == v)
            val = R3[(u * 9 + u) * 9 + w] + R3[(u * 9 + w) * 9 + u] +
                  R3[(w * 9 + u) * 9 + u];
          else if (v == w)
            val = R3[(u * 9 + v) * 9 + v] + R3[(v * 9 + u) * 9 + v] +
                  R3[(v * 9 + v) * 9 + u];
          else
            val = R3[(u * 9 + v) * 9 + w] + R3[(u * 9 + w) * 9 + v] +
                  R3[(v * 9 + u) * 9 + w] + R3[(v * 9 + w) * 9 + u] +
                  R3[(w * 9 + u) * 9 + v] + R3[(w * 9 + v) * 9 + u];
        }
      }
    }
    Tg[i] = val;
  }
}

// --- symmetric contraction: triangular Horner over fully-sym table.
//     thread = 1 node x 1 channel; cb via uniform s_load (SMEM path).
//     grid = (c-swizzled 128, chunk): co-resident blocks (stride 256)
//     share (e,c) -> scalar-cache-shared coeff stream (R21 property);
//     c = (bx&7)*16 + (bx>>3) -> XCD bx%8 owns contiguous c-range
//     [16j,16j+16) = 9 exact cache lines per node row (no over-fetch).
__global__ __launch_bounds__(BLK, 8) void contract_kernel(
    const float* __restrict__ feats, const float* __restrict__ table,
    const int* __restrict__ order, const int* __restrict__ offs,
    float* __restrict__ tmp, int NPAD) {
  const int bx = blockIdx.x;                  // 0..127
  const int c = ((bx & 7) << 4) | (bx >> 3);  // XCD-contiguous c ranges
  // map global chunk -> (element e, node range) ; wave-uniform
  int rem = blockIdx.y;
  int e = -1, pbase = 0, segend = 0;
#pragma unroll
  for (int k = 0; k < NE; ++k) {
    int st = offs[k], en = offs[k + 1];
    int nc = (en - st + BLK - 1) >> 8;        // chunks in segment k (BLK=256)
    if (e < 0) {
      if (rem < nc) { e = k; pbase = st + rem * BLK; segend = en; }
      else rem -= nc;
    }
  }
  if (e < 0) return;                          // slack chunk

  const int p = pbase + threadIdx.x;
  const bool valid = (p < segend);
  const int n = order[valid ? p : (segend - 1)];  // clamp: stay in-bounds

  float tf[LDIM];
  {
    const float* xp = feats + ((size_t)n * CCH + c) * LDIM;
#pragma unroll
    for (int q = 0; q < LDIM; ++q) tf[q] = xp[q];
  }

  const float* Tc = table + (size_t)(e * CCH + c) * TGSTR;

#pragma unroll 1
  for (int dd = 0; dd < 4; ++dd) {
    // wave-uniform address (blockIdx/dd only) -> s_load (SMEM path)
    const float* B = Tc + dd * TSTR;
    int idx = 0;                              // folds to constants on unroll
    float acc = 0.f;
#pragma unroll
    for (int u = 0; u < 9; ++u) {
      float inner = B[idx++];                 // T1s[u]
#pragma unroll
      for (int v = u; v < 9; ++v) {
        float Hv = B[idx++];                  // T2sym[u][v]
#pragma unroll
        for (int w = v; w < 9; ++w)
          Hv = fmaf(B[idx++], tf[w], Hv);
        inner = fmaf(Hv, tf[v], inner);
      }
      acc = fmaf(inner, tf[u], acc);
    }
    if (valid) tmp[((size_t)dd * CCH + c) * NPAD + p] = acc;
  }
}

// ------------- o3.Linear + residual, fused over dd via blockIdx.z.
// block = 256 lanes = nodes; blockIdx = (chunk, c1-group of 32, dd).
// All scalar addressing blockIdx-derived -> W rows via s_load (SMEM path).
// Per ci: 1 coalesced A dword + 2x s_load_dwordx16 + 32 FMA.
// dd=0: out[:, c1] = A0 @ W0 ; dd>=1: out[:, 128+3*c1+(dd-1)] = A_dd @ W1.
__global__ __launch_bounds__(BLK, 6) void linear_kernel(
    const float* __restrict__ tmp, const float* __restrict__ W0,
    const float* __restrict__ W1, const float* __restrict__ sc,
    const int* __restrict__ order, float* __restrict__ out, int N, int NPAD) {
  const int t = threadIdx.x;
  const int p = blockIdx.x * BLK + t;
  const int c1b = blockIdx.y * 32;            // block-uniform
  const int dd = blockIdx.z;                  // 0..3, block-uniform
  const int pc = (p < N) ? p : (N - 1);

  __shared__ float SR[BLK * 36];

  const float* Ap = tmp + (size_t)dd * CCH * NPAD + pc;   // lane-coalesced
  const float* Wb = ((dd == 0) ? W0 : W1) + c1b;  // block-uniform -> s_load

  float acc[32];
#pragma unroll
  for (int k = 0; k < 32; ++k) acc[k] = 0.f;

#pragma unroll 4
  for (int ci = 0; ci < CCH; ++ci) {
    const float a = Ap[(size_t)ci * NPAD];
    const float* wr = Wb + ci * CCH;          // uniform -> 2x s_load_dwordx16
#pragma unroll
    for (int k = 0; k < 32; ++k)
      acc[k] = fmaf(a, wr[k], acc[k]);
  }

  const float s = 0.08838834764831843f;       // 1/sqrt(128)
#pragma unroll
  for (int k = 0; k < 32; ++k) SR[t * 36 + k] = acc[k] * s;
  __syncthreads();

  if (dd == 0) {
    // flush: 256 nodes x 8 float4 (32 cols), + sc residual
#pragma unroll
    for (int k = 0; k < 8; ++k) {
      const int idx = t + k * BLK;
      const int node = idx >> 3, f = idx & 7;
      const int p2 = blockIdx.x * BLK + node;
      if (p2 < N) {
        const int n = order[p2];
        const int gcol = c1b + f * 4;
        float4 v;
        v.x = SR[node * 36 + f * 4 + 0];
        v.y = SR[node * 36 + f * 4 + 1];
        v.z = SR[node * 36 + f * 4 + 2];
        v.w = SR[node * 36 + f * 4 + 3];
        const float4 sv = *(const float4*)(sc + (size_t)n * 512 + gcol);
        v.x += sv.x; v.y += sv.y; v.z += sv.z; v.w += sv.w;
        *(float4*)(out + (size_t)n * 512 + gcol) = v;
      }
    }
  } else {
    // flush: 32 rounds x (8 nodes x 32 stride-3 dwords), + sc residual
    const int jj = t & 31;                    // col within group
    const int nb0 = t >> 5;                   // node sub-index 0..7
#pragma unroll 1
    for (int nb = 0; nb < 32; ++nb) {
      const int node = nb0 + nb * 8;
      const int p2 = blockIdx.x * BLK + node;
      if (p2 < N) {
        const int n = order[p2];
        const int gcol = CCH + 3 * (c1b + jj) + (dd - 1);
        const float v = SR[node * 36 + jj];
        out[(size_t)n * 512 + gcol] = v + sc[(size_t)n * 512 + gcol];
      }
    }
  }
}

// -------------------------------------------------------------------- launch
extern "C" void kernel_launch(void* const* d_in, const int* in_sizes, int n_in,
                              void* d_out, int out_size, void* d_ws, size_t ws_size,
                              hipStream_t stream) {
  const float* feats = (const float*)d_in[0];
  const float* attrs = (const float*)d_in[1];
  const float* sc    = (const float*)d_in[2];
  const float* U3_0  = (const float*)d_in[3];
  const float* U2_0  = (const float*)d_in[4];
  const float* U1_0  = (const float*)d_in[5];
  const float* w3_0  = (const float*)d_in[6];
  const float* w2_0  = (const float*)d_in[7];
  const float* w1_0  = (const float*)d_in[8];
  const float* U3_1  = (const float*)d_in[9];
  const float* U2_1  = (const float*)d_in[10];
  const float* U1_1  = (const float*)d_in[11];
  const float* w3_1  = (const float*)d_in[12];
  const float* w2_1  = (const float*)d_in[13];
  const float* w1_1  = (const float*)d_in[14];
  const float* W0    = (const float*)d_in[15];
  const float* W1    = (const float*)d_in[16];

  const int N = in_sizes[0] / (CCH * LDIM);     // 10000
  const int NPAD = ((N + 15) & ~15) + 16;       // 10016

  // ws (floats): table[5*128*TGSTR] | tmp[4*C][NPAD] | order elem offs(8) cur(8) gcnt(8)
  float* table = (float*)d_ws;
  float* tmp   = table + (size_t)NE * CCH * TGSTR;
  int*   order = (int*)(tmp + (size_t)4 * CCH * NPAD);
  int*   elem  = order + N;
  int*   offs  = elem + N;
  int*   cur   = offs + 8;
  int*   gcnt  = cur + 8;                       // gcnt[0..4], gcnt[5]=done
  float* out   = (float*)d_out;

  hipMemsetAsync(gcnt, 0, 8 * sizeof(int), stream);

  const int nblk = (N + BLK - 1) / BLK;
  count_offs_kernel<<<dim3(nblk), dim3(BLK), 0, stream>>>(
      attrs, N, elem, gcnt, offs, cur);
  scatter_kernel<<<dim3(nblk), dim3(BLK), 0, stream>>>(elem, N, cur, order);

  table_kernel<<<dim3(NE * CCH, 4), dim3(BLK), 0, stream>>>(
      U3_0, U2_0, U1_0, U3_1, U2_1, U1_1,
      w3_0, w2_0, w1_0, w3_1, w2_1, w1_1, table);

  // compact chunk grid: sum over e of ceil(cnt_e/BLK) <= N/BLK + NE
  const int chunksMax = (N + BLK - 1) / BLK + NE;
  contract_kernel<<<dim3(CCH, chunksMax), dim3(BLK), 0, stream>>>(
      feats, table, order, offs, tmp, NPAD);

  const int nchunk = (N + BLK - 1) / BLK;       // 40 (== 0 mod 8)
  linear_kernel<<<dim3(nchunk, 4, 4), dim3(BLK), 0, stream>>>(
      tmp, W0, W1, sc, order, out, N, NPAD);
}

// Round 13
// 238.925 us; speedup vs baseline: 1.0394x; 1.0394x over previous
//
#include <hip/hip_runtime.h>

// EquivariantProductBasisBlock (MACE symmetric contraction, corr=3) + o3.Linear
// N=10000 nodes, C=128 channels, L=9 (lmax=2), E=5 elements, fp32 throughout.
//
// R26 changes vs R25 (linear only; contract/table/sort frozen):
//  - R25 post-mortem: c1-tile 16->32 halved waves, linear got SLOWER
//    (50.5->60us, occ 42->21%). Scaling law across R15/16/24/25: hipcc
//    sinks A-loads to use (1 in flight); linear time = 128-load chain
//    x ~200cy / waves-per-CU. Intensity doesn't matter; TLP divides.
//  - R26: c1-tile 16->8. Grid (40,16,4)=2560 blocks=10240 waves=40/CU
//    (oversubscribed -> occupancy ceiling ~100%). Per ci: 1 A dword +
//    s_load_dwordx8 + 8 FMA. VGPR ~16, LDS 12KB. Sibling blocks still
//    XCD-co-located (stride 40 = 0 mod 8) -> A re-reads L2-local.

#define CCH 128
#define LDIM 9
#define NE 5
#define BLK 256
#define TSTR 220             // coeffs per (e,c,dd): 219 + 1 pad (16B-aligned)
#define TGSTR 880            // per (e,c) = 4*TSTR
#define U3LDS 8748           // staged U3 slice (729*12 max)

// -------------------------------------------- sort: count + offs (fused)
__global__ __launch_bounds__(BLK) void count_offs_kernel(
    const float* __restrict__ attrs, int N,
    int* __restrict__ elem, int* __restrict__ gcnt,   // gcnt[5], gcnt[5]=done
    int* __restrict__ offs, int* __restrict__ cur) {
  int n = blockIdx.x * BLK + threadIdx.x;
  int e = 0;
  if (n < N) {
    const float* a = attrs + n * NE;
#pragma unroll
    for (int j = 1; j < NE; ++j)
      if (a[j] > 0.5f) e = j;
    elem[n] = e;
  }
  int lane = threadIdx.x & 63;
#pragma unroll
  for (int k = 0; k < NE; ++k) {
    unsigned long long m = __ballot(n < N && e == k);
    if (m) {
      int leader = __ffsll((long long)m) - 1;
      if (lane == leader) atomicAdd(&gcnt[k], __popcll(m));
    }
  }
  __threadfence();
  __syncthreads();
  if (threadIdx.x == 0) {
    int t = atomicAdd(&gcnt[NE], 1);
    if (t == (int)gridDim.x - 1) {            // last block: prefix sum
      int acc = 0;
      for (int k = 0; k < NE; ++k) {
        int ck = atomicAdd(&gcnt[k], 0);      // coherent read
        offs[k] = acc; cur[k] = acc; acc += ck;
      }
      offs[NE] = acc;
    }
  }
}

// ----------------------------------------------------------- sort: scatter
__global__ __launch_bounds__(BLK) void scatter_kernel(
    const int* __restrict__ elem, int N,
    int* __restrict__ cur, int* __restrict__ order) {
  int n = blockIdx.x * BLK + threadIdx.x;
  if (n >= N) return;
  int e = elem[n];
  int lane = threadIdx.x & 63;
#pragma unroll
  for (int k = 0; k < NE; ++k) {
    if (e == k) {
      unsigned long long m = __ballot(1);
      int cnt = __popcll(m);
      int leader = __ffsll((long long)m) - 1;
      int base = 0;
      if (lane == leader) base = atomicAdd(&cur[k], cnt);
      base = __shfl(base, leader);
      int rank = __popcll(m & ((1ull << lane) - 1ull));
      order[base + rank] = n;
    }
  }
}

// ---- build + FULLY (u,v,w)-symmetrize + pack U(x)w tables (one dd/block)
__global__ __launch_bounds__(BLK) void table_kernel(
    const float* __restrict__ U3_0, const float* __restrict__ U2_0,
    const float* __restrict__ U1_0, const float* __restrict__ U3_1,
    const float* __restrict__ U2_1, const float* __restrict__ U1_1,
    const float* __restrict__ w3_0, const float* __restrict__ w2_0,
    const float* __restrict__ w1_0, const float* __restrict__ w3_1,
    const float* __restrict__ w2_1, const float* __restrict__ w1_1,
    float* __restrict__ table) {
  const int b = blockIdx.x;        // e*CCH + c
  const int dd = blockIdx.y;       // 0..3
  const int e = b / CCH, c = b % CCH;
  float* Tg = table + (size_t)b * TGSTR + dd * TSTR;
  __shared__ float Us[U3LDS];      // raw U3 slice [729*K3]
  __shared__ float U2s[324];       // raw U2 slice [81*K2]
  __shared__ float R3[729];        // rect T3
  __shared__ float R2[81];
  __shared__ float R1l[9];
  __shared__ float w3l[12], w2l[4];
  const int tid = threadIdx.x;
  const int d = dd - 1;
  const int K3 = (dd == 0) ? 10 : 12;
  const int K2 = (dd == 0) ? 3 : 4;

  if (dd == 0) {
    for (int i = tid; i < 7290; i += BLK) Us[i] = U3_0[i];
    for (int i = tid; i < 243; i += BLK)  U2s[i] = U2_0[i];
    if (tid < 10) w3l[tid] = w3_0[(e * 10 + tid) * CCH + c];
    else if (tid < 13) w2l[tid - 10] = w2_0[(e * 3 + (tid - 10)) * CCH + c];
    if (tid < 9) R1l[tid] = U1_0[tid] * w1_0[e * CCH + c];
  } else {
    for (int i = tid; i < 8748; i += BLK) Us[i] = U3_1[d * 8748 + i];
    for (int i = tid; i < 324; i += BLK)  U2s[i] = U2_1[d * 324 + i];
    if (tid < 12) w3l[tid] = w3_1[(e * 12 + tid) * CCH + c];
    else if (tid < 16) w2l[tid - 12] = w2_1[(e * 4 + (tid - 12)) * CCH + c];
    if (tid < 9) R1l[tid] = U1_1[d * 9 + tid] * w1_1[e * CCH + c];
  }
  __syncthreads();
  for (int r = tid; r < 729; r += BLK) {
    float acc = 0.f;
    for (int k = 0; k < K3; ++k) acc += Us[r * K3 + k] * w3l[k];
    R3[r] = acc;
  }
  for (int q = tid; q < 81; q += BLK) {
    float acc = 0.f;
    for (int k = 0; k < K2; ++k) acc += U2s[q * K2 + k] * w2l[k];
    R2[q] = acc;
  }
  __syncthreads();
  // pack: Horner consumption order. Per u: [T1s[u], then per v=u..8:
  //   [T2s[u][v], S3s[u][v][w] for w=v..8]].  Per-u size = (10-u)(11-u)/2.
  for (int i = tid; i < TSTR; i += BLK) {
    float val = 0.f;
    if (i < 219) {
      int rem = i, u = 0;
      while (rem >= (10 - u) * (11 - u) / 2) {
        rem -= (10 - u) * (11 - u) / 2; ++u;
      }
      if (rem == 0) {
        val = R1l[u];
      } else {
        rem -= 1;
        int v = u;
        while (rem >= 10 - v) { rem -= 10 - v; ++v; }
        if (rem == 0) {
          val = (u == v) ? R2[u * 9 + v] : R2[u * 9 + v] + R2[v * 9 + u];
        } else {
          int w = v + (rem - 1);
          if (u == v && v == w)
            val = R3[(u * 9 + u) * 9 + u];
          else if (u == v)
            val = R3[(u * 9 + u) * 9 + w] + R3[(u * 9 + w) * 9 + u] +
                  R3[(w * 9 + u) * 9 + u];
          else if (v == w)
            val = R3[(u * 9 + v) * 9 + v] + R3[(v * 9 + u) * 9 + v] +
                  R3[(v * 9 + v) * 9 + u];
          else
            val = R3[(u * 9 + v) * 9 + w] + R3[(u * 9 + w) * 9 + v] +
                  R3[(v * 9 + u) * 9 + w] + R3[(v * 9 + w) * 9 + u] +
                  R3[(w * 9 + u) * 9 + v] + R3[(w * 9 + v) * 9 + u];
        }
      }
    }
    Tg[i] = val;
  }
}

// --- symmetric contraction: triangular Horner over fully-sym table.
//     thread = 1 node x 1 channel; cb via uniform s_load (SMEM path).
//     grid = (c-swizzled 128, chunk): co-resident blocks (stride 256)
//     share (e,c) -> scalar-cache-shared coeff stream (R21 property);
//     c = (bx&7)*16 + (bx>>3) -> XCD bx%8 owns contiguous c-range
//     [16j,16j+16) = 9 exact cache lines per node row (no over-fetch).
__global__ __launch_bounds__(BLK, 8) void contract_kernel(
    const float* __restrict__ feats, const float* __restrict__ table,
    const int* __restrict__ order, const int* __restrict__ offs,
    float* __restrict__ tmp, int NPAD) {
  const int bx = blockIdx.x;                  // 0..127
  const int c = ((bx & 7) << 4) | (bx >> 3);  // XCD-contiguous c ranges
  // map global chunk -> (element e, node range) ; wave-uniform
  int rem = blockIdx.y;
  int e = -1, pbase = 0, segend = 0;
#pragma unroll
  for (int k = 0; k < NE; ++k) {
    int st = offs[k], en = offs[k + 1];
    int nc = (en - st + BLK - 1) >> 8;        // chunks in segment k (BLK=256)
    if (e < 0) {
      if (rem < nc) { e = k; pbase = st + rem * BLK; segend = en; }
      else rem -= nc;
    }
  }
  if (e < 0) return;                          // slack chunk

  const int p = pbase + threadIdx.x;
  const bool valid = (p < segend);
  const int n = order[valid ? p : (segend - 1)];  // clamp: stay in-bounds

  float tf[LDIM];
  {
    const float* xp = feats + ((size_t)n * CCH + c) * LDIM;
#pragma unroll
    for (int q = 0; q < LDIM; ++q) tf[q] = xp[q];
  }

  const float* Tc = table + (size_t)(e * CCH + c) * TGSTR;

#pragma unroll 1
  for (int dd = 0; dd < 4; ++dd) {
    // wave-uniform address (blockIdx/dd only) -> s_load (SMEM path)
    const float* B = Tc + dd * TSTR;
    int idx = 0;                              // folds to constants on unroll
    float acc = 0.f;
#pragma unroll
    for (int u = 0; u < 9; ++u) {
      float inner = B[idx++];                 // T1s[u]
#pragma unroll
      for (int v = u; v < 9; ++v) {
        float Hv = B[idx++];                  // T2sym[u][v]
#pragma unroll
        for (int w = v; w < 9; ++w)
          Hv = fmaf(B[idx++], tf[w], Hv);
        inner = fmaf(Hv, tf[v], inner);
      }
      acc = fmaf(inner, tf[u], acc);
    }
    if (valid) tmp[((size_t)dd * CCH + c) * NPAD + p] = acc;
  }
}

// ------------- o3.Linear + residual, fused over dd via blockIdx.z.
// block = 256 lanes = nodes; blockIdx = (chunk, c1-group of 8, dd).
// All scalar addressing blockIdx-derived -> W rows via s_load (SMEM path).
// Per ci: 1 coalesced A dword + s_load_dwordx8 + 8 FMA. 10240 waves total
// (40/CU oversubscribed) -> the 128-load latency chain is TLP-divided.
// dd=0: out[:, c1] = A0 @ W0 ; dd>=1: out[:, 128+3*c1+(dd-1)] = A_dd @ W1.
__global__ __launch_bounds__(BLK, 8) void linear_kernel(
    const float* __restrict__ tmp, const float* __restrict__ W0,
    const float* __restrict__ W1, const float* __restrict__ sc,
    const int* __restrict__ order, float* __restrict__ out, int N, int NPAD) {
  const int t = threadIdx.x;
  const int p = blockIdx.x * BLK + t;
  const int c1b = blockIdx.y * 8;             // block-uniform
  const int dd = blockIdx.z;                  // 0..3, block-uniform
  const int pc = (p < N) ? p : (N - 1);

  __shared__ float SR[BLK * 12];

  const float* Ap = tmp + (size_t)dd * CCH * NPAD + pc;   // lane-coalesced
  const float* Wb = ((dd == 0) ? W0 : W1) + c1b;  // block-uniform -> s_load

  float acc[8];
#pragma unroll
  for (int k = 0; k < 8; ++k) acc[k] = 0.f;

#pragma unroll 4
  for (int ci = 0; ci < CCH; ++ci) {
    const float a = Ap[(size_t)ci * NPAD];
    const float* wr = Wb + ci * CCH;          // uniform -> s_load_dwordx8
#pragma unroll
    for (int k = 0; k < 8; ++k)
      acc[k] = fmaf(a, wr[k], acc[k]);
  }

  const float s = 0.08838834764831843f;       // 1/sqrt(128)
#pragma unroll
  for (int k = 0; k < 8; ++k) SR[t * 12 + k] = acc[k] * s;
  __syncthreads();

  if (dd == 0) {
    // flush: 256 nodes x 2 float4 (8 cols), + sc residual
#pragma unroll
    for (int k = 0; k < 2; ++k) {
      const int idx = t + k * BLK;
      const int node = idx >> 1, f = idx & 1;
      const int p2 = blockIdx.x * BLK + node;
      if (p2 < N) {
        const int n = order[p2];
        const int gcol = c1b + f * 4;
        float4 v;
        v.x = SR[node * 12 + f * 4 + 0];
        v.y = SR[node * 12 + f * 4 + 1];
        v.z = SR[node * 12 + f * 4 + 2];
        v.w = SR[node * 12 + f * 4 + 3];
        const float4 sv = *(const float4*)(sc + (size_t)n * 512 + gcol);
        v.x += sv.x; v.y += sv.y; v.z += sv.z; v.w += sv.w;
        *(float4*)(out + (size_t)n * 512 + gcol) = v;
      }
    }
  } else {
    // flush: 8 rounds x (32 nodes x 8 stride-3 dwords), + sc residual
    const int jj = t & 7;                     // col within group
    const int nb0 = t >> 3;                   // node sub-index 0..31
#pragma unroll 1
    for (int nb = 0; nb < 8; ++nb) {
      const int node = nb0 + nb * 32;
      const int p2 = blockIdx.x * BLK + node;
      if (p2 < N) {
        const int n = order[p2];
        const int gcol = CCH + 3 * (c1b + jj) + (dd - 1);
        const float v = SR[node * 12 + jj];
        out[(size_t)n * 512 + gcol] = v + sc[(size_t)n * 512 + gcol];
      }
    }
  }
}

// -------------------------------------------------------------------- launch
extern "C" void kernel_launch(void* const* d_in, const int* in_sizes, int n_in,
                              void* d_out, int out_size, void* d_ws, size_t ws_size,
                              hipStream_t stream) {
  const float* feats = (const float*)d_in[0];
  const float* attrs = (const float*)d_in[1];
  const float* sc    = (const float*)d_in[2];
  const float* U3_0  = (const float*)d_in[3];
  const float* U2_0  = (const float*)d_in[4];
  const float* U1_0  = (const float*)d_in[5];
  const float* w3_0  = (const float*)d_in[6];
  const float* w2_0  = (const float*)d_in[7];
  const float* w1_0  = (const float*)d_in[8];
  const float* U3_1  = (const float*)d_in[9];
  const float* U2_1  = (const float*)d_in[10];
  const float* U1_1  = (const float*)d_in[11];
  const float* w3_1  = (const float*)d_in[12];
  const float* w2_1  = (const float*)d_in[13];
  const float* w1_1  = (const float*)d_in[14];
  const float* W0    = (const float*)d_in[15];
  const float* W1    = (const float*)d_in[16];

  const int N = in_sizes[0] / (CCH * LDIM);     // 10000
  const int NPAD = ((N + 15) & ~15) + 16;       // 10016

  // ws (floats): table[5*128*TGSTR] | tmp[4*C][NPAD] | order elem offs(8) cur(8) gcnt(8)
  float* table = (float*)d_ws;
  float* tmp   = table + (size_t)NE * CCH * TGSTR;
  int*   order = (int*)(tmp + (size_t)4 * CCH * NPAD);
  int*   elem  = order + N;
  int*   offs  = elem + N;
  int*   cur   = offs + 8;
  int*   gcnt  = cur + 8;                       // gcnt[0..4], gcnt[5]=done
  float* out   = (float*)d_out;

  hipMemsetAsync(gcnt, 0, 8 * sizeof(int), stream);

  const int nblk = (N + BLK - 1) / BLK;
  count_offs_kernel<<<dim3(nblk), dim3(BLK), 0, stream>>>(
      attrs, N, elem, gcnt, offs, cur);
  scatter_kernel<<<dim3(nblk), dim3(BLK), 0, stream>>>(elem, N, cur, order);

  table_kernel<<<dim3(NE * CCH, 4), dim3(BLK), 0, stream>>>(
      U3_0, U2_0, U1_0, U3_1, U2_1, U1_1,
      w3_0, w2_0, w1_0, w3_1, w2_1, w1_1, table);

  // compact chunk grid: sum over e of ceil(cnt_e/BLK) <= N/BLK + NE
  const int chunksMax = (N + BLK - 1) / BLK + NE;
  contract_kernel<<<dim3(CCH, chunksMax), dim3(BLK), 0, stream>>>(
      feats, table, order, offs, tmp, NPAD);

  const int nchunk = (N + BLK - 1) / BLK;       // 40 (== 0 mod 8)
  linear_kernel<<<dim3(nchunk, 16, 4), dim3(BLK), 0, stream>>>(
      tmp, W0, W1, sc, order, out, N, NPAD);
}

// Round 14
// 236.579 us; speedup vs baseline: 1.0497x; 1.0099x over previous
//
#include <hip/hip_runtime.h>

// EquivariantProductBasisBlock (MACE symmetric contraction, corr=3) + o3.Linear
// N=10000 nodes, C=128 channels, L=9 (lmax=2), E=5 elements, fp32 throughout.
//
// R27 changes vs R26 (tmp layout + linear inner loop; all else frozen):
//  - R26 post-mortem: tile 16->8 doubled waves but dur flat (50.5->50.3)
//    -> TLP saturated. Invariant = per-wave chain of 128 sequential
//    {A dword + W s_load + wait + FMA} links (hipcc sinks loads; VGPR=16
//    proves ~1 in flight). Lever left: CHAIN LENGTH.
//  - R27: tmp re-laid out as [dd][cq][p][q] (ci-quads). Linear loads one
//    float4 = 4 ci per link (lanes at 16B stride -> still 1KB coalesced
//    wave-load); the 4 W-row s_loads per quad batch behind one lgkmcnt.
//    Chain 128 -> 32 links. Per link: 1 vec load + 4 s_load_dwordx8 +
//    32 FMA.
//  - contract stores become 16B-strided dwords; quad-sibling c-blocks
//    (bx, bx+8, bx+16, bx+24 -> same XCD under the c-swizzle) fill each
//    64B line in that XCD's L2 -> HBM write bytes unchanged (~+2us TA).

#define CCH 128
#define LDIM 9
#define NE 5
#define BLK 256
#define TSTR 220             // coeffs per (e,c,dd): 219 + 1 pad (16B-aligned)
#define TGSTR 880            // per (e,c) = 4*TSTR
#define U3LDS 8748           // staged U3 slice (729*12 max)

// -------------------------------------------- sort: count + offs (fused)
__global__ __launch_bounds__(BLK) void count_offs_kernel(
    const float* __restrict__ attrs, int N,
    int* __restrict__ elem, int* __restrict__ gcnt,   // gcnt[5], gcnt[5]=done
    int* __restrict__ offs, int* __restrict__ cur) {
  int n = blockIdx.x * BLK + threadIdx.x;
  int e = 0;
  if (n < N) {
    const float* a = attrs + n * NE;
#pragma unroll
    for (int j = 1; j < NE; ++j)
      if (a[j] > 0.5f) e = j;
    elem[n] = e;
  }
  int lane = threadIdx.x & 63;
#pragma unroll
  for (int k = 0; k < NE; ++k) {
    unsigned long long m = __ballot(n < N && e == k);
    if (m) {
      int leader = __ffsll((long long)m) - 1;
      if (lane == leader) atomicAdd(&gcnt[k], __popcll(m));
    }
  }
  __threadfence();
  __syncthreads();
  if (threadIdx.x == 0) {
    int t = atomicAdd(&gcnt[NE], 1);
    if (t == (int)gridDim.x - 1) {            // last block: prefix sum
      int acc = 0;
      for (int k = 0; k < NE; ++k) {
        int ck = atomicAdd(&gcnt[k], 0);      // coherent read
        offs[k] = acc; cur[k] = acc; acc += ck;
      }
      offs[NE] = acc;
    }
  }
}

// ----------------------------------------------------------- sort: scatter
__global__ __launch_bounds__(BLK) void scatter_kernel(
    const int* __restrict__ elem, int N,
    int* __restrict__ cur, int* __restrict__ order) {
  int n = blockIdx.x * BLK + threadIdx.x;
  if (n >= N) return;
  int e = elem[n];
  int lane = threadIdx.x & 63;
#pragma unroll
  for (int k = 0; k < NE; ++k) {
    if (e == k) {
      unsigned long long m = __ballot(1);
      int cnt = __popcll(m);
      int leader = __ffsll((long long)m) - 1;
      int base = 0;
      if (lane == leader) base = atomicAdd(&cur[k], cnt);
      base = __shfl(base, leader);
      int rank = __popcll(m & ((1ull << lane) - 1ull));
      order[base + rank] = n;
    }
  }
}

// ---- build + FULLY (u,v,w)-symmetrize + pack U(x)w tables (one dd/block)
__global__ __launch_bounds__(BLK) void table_kernel(
    const float* __restrict__ U3_0, const float* __restrict__ U2_0,
    const float* __restrict__ U1_0, const float* __restrict__ U3_1,
    const float* __restrict__ U2_1, const float* __restrict__ U1_1,
    const float* __restrict__ w3_0, const float* __restrict__ w2_0,
    const float* __restrict__ w1_0, const float* __restrict__ w3_1,
    const float* __restrict__ w2_1, const float* __restrict__ w1_1,
    float* __restrict__ table) {
  const int b = blockIdx.x;        // e*CCH + c
  const int dd = blockIdx.y;       // 0..3
  const int e = b / CCH, c = b % CCH;
  float* Tg = table + (size_t)b * TGSTR + dd * TSTR;
  __shared__ float Us[U3LDS];      // raw U3 slice [729*K3]
  __shared__ float U2s[324];       // raw U2 slice [81*K2]
  __shared__ float R3[729];        // rect T3
  __shared__ float R2[81];
  __shared__ float R1l[9];
  __shared__ float w3l[12], w2l[4];
  const int tid = threadIdx.x;
  const int d = dd - 1;
  const int K3 = (dd == 0) ? 10 : 12;
  const int K2 = (dd == 0) ? 3 : 4;

  if (dd == 0) {
    for (int i = tid; i < 7290; i += BLK) Us[i] = U3_0[i];
    for (int i = tid; i < 243; i += BLK)  U2s[i] = U2_0[i];
    if (tid < 10) w3l[tid] = w3_0[(e * 10 + tid) * CCH + c];
    else if (tid < 13) w2l[tid - 10] = w2_0[(e * 3 + (tid - 10)) * CCH + c];
    if (tid < 9) R1l[tid] = U1_0[tid] * w1_0[e * CCH + c];
  } else {
    for (int i = tid; i < 8748; i += BLK) Us[i] = U3_1[d * 8748 + i];
    for (int i = tid; i < 324; i += BLK)  U2s[i] = U2_1[d * 324 + i];
    if (tid < 12) w3l[tid] = w3_1[(e * 12 + tid) * CCH + c];
    else if (tid < 16) w2l[tid - 12] = w2_1[(e * 4 + (tid - 12)) * CCH + c];
    if (tid < 9) R1l[tid] = U1_1[d * 9 + tid] * w1_1[e * CCH + c];
  }
  __syncthreads();
  for (int r = tid; r < 729; r += BLK) {
    float acc = 0.f;
    for (int k = 0; k < K3; ++k) acc += Us[r * K3 + k] * w3l[k];
    R3[r] = acc;
  }
  for (int q = tid; q < 81; q += BLK) {
    float acc = 0.f;
    for (int k = 0; k < K2; ++k) acc += U2s[q * K2 + k] * w2l[k];
    R2[q] = acc;
  }
  __syncthreads();
  // pack: Horner consumption order. Per u: [T1s[u], then per v=u..8:
  //   [T2s[u][v], S3s[u][v][w] for w=v..8]].  Per-u size = (10-u)(11-u)/2.
  for (int i = tid; i < TSTR; i += BLK) {
    float val = 0.f;
    if (i < 219) {
      int rem = i, u = 0;
      while (rem >= (10 - u) * (11 - u) / 2) {
        rem -= (10 - u) * (11 - u) / 2; ++u;
      }
      if (rem == 0) {
        val = R1l[u];
      } else {
        rem -= 1;
        int v = u;
        while (rem >= 10 - v) { rem -= 10 - v; ++v; }
        if (rem == 0) {
          val = (u == v) ? R2[u * 9 + v] : R2[u * 9 + v] + R2[v * 9 + u];
        } else {
          int w = v + (rem - 1);
          if (u == v && v == w)
            val = R3[(u * 9 + u) * 9 + u];
          else if (u == v)
            val = R3[(u * 9 + u) * 9 + w] + R3[(u * 9 + w) * 9 + u] +
                  R3[(w * 9 + u) * 9 + u];
          else if (v == w)
            val = R3[(u * 9 + v) * 9 + v] + R3[(v * 9 + u) * 9 + v] +
                  R3[(v * 9 + v) * 9 + u];
          else
            val = R3[(u * 9 + v) * 9 + w] + R3[(u * 9 + w) * 9 + v] +
                  R3[(v * 9 + u) * 9 + w] + R3[(v * 9 + w) * 9 + u] +
                  R3[(w * 9 + u) * 9 + v] + R3[(w * 9 + v) * 9 + u];
        }
      }
    }
    Tg[i] = val;
  }
}

// --- symmetric contraction: triangular Horner over fully-sym table.
//     thread = 1 node x 1 channel; cb via uniform s_load (SMEM path).
//     grid = (c-swizzled 128, chunk): co-resident blocks (stride 256)
//     share (e,c) -> scalar-cache-shared coeff stream; c-swizzle keeps
//     XCD bx%8 on contiguous c-ranges (R24 properties, both proven).
//     Store: packed ci-quad layout tmp[dd][c>>2][p][c&3]; quad-sibling
//     c-blocks share an XCD -> lines merge in L2.
__global__ __launch_bounds__(BLK, 8) void contract_kernel(
    const float* __restrict__ feats, const float* __restrict__ table,
    const int* __restrict__ order, const int* __restrict__ offs,
    float* __restrict__ tmp, int NPAD) {
  const int bx = blockIdx.x;                  // 0..127
  const int c = ((bx & 7) << 4) | (bx >> 3);  // XCD-contiguous c ranges
  // map global chunk -> (element e, node range) ; wave-uniform
  int rem = blockIdx.y;
  int e = -1, pbase = 0, segend = 0;
#pragma unroll
  for (int k = 0; k < NE; ++k) {
    int st = offs[k], en = offs[k + 1];
    int nc = (en - st + BLK - 1) >> 8;        // chunks in segment k (BLK=256)
    if (e < 0) {
      if (rem < nc) { e = k; pbase = st + rem * BLK; segend = en; }
      else rem -= nc;
    }
  }
  if (e < 0) return;                          // slack chunk

  const int p = pbase + threadIdx.x;
  const bool valid = (p < segend);
  const int n = order[valid ? p : (segend - 1)];  // clamp: stay in-bounds

  float tf[LDIM];
  {
    const float* xp = feats + ((size_t)n * CCH + c) * LDIM;
#pragma unroll
    for (int q = 0; q < LDIM; ++q) tf[q] = xp[q];
  }

  const float* Tc = table + (size_t)(e * CCH + c) * TGSTR;
  const int cq = c >> 2, qq = c & 3;

#pragma unroll 1
  for (int dd = 0; dd < 4; ++dd) {
    // wave-uniform address (blockIdx/dd only) -> s_load (SMEM path)
    const float* B = Tc + dd * TSTR;
    int idx = 0;                              // folds to constants on unroll
    float acc = 0.f;
#pragma unroll
    for (int u = 0; u < 9; ++u) {
      float inner = B[idx++];                 // T1s[u]
#pragma unroll
      for (int v = u; v < 9; ++v) {
        float Hv = B[idx++];                  // T2sym[u][v]
#pragma unroll
        for (int w = v; w < 9; ++w)
          Hv = fmaf(B[idx++], tf[w], Hv);
        inner = fmaf(Hv, tf[v], inner);
      }
      acc = fmaf(inner, tf[u], acc);
    }
    if (valid)
      tmp[(((size_t)(dd * 32 + cq)) * NPAD + p) * 4 + qq] = acc;
  }
}

// ------------- o3.Linear + residual, fused over dd via blockIdx.z.
// block = 256 lanes = nodes; blockIdx = (chunk, c1-group of 8, dd).
// A in packed ci-quad layout: one float4 = 4 ci per chain link (32 links,
// was 128); the 4 W-row s_loads per quad batch behind one lgkmcnt.
// dd=0: out[:, c1] = A0 @ W0 ; dd>=1: out[:, 128+3*c1+(dd-1)] = A_dd @ W1.
__global__ __launch_bounds__(BLK, 8) void linear_kernel(
    const float* __restrict__ tmp, const float* __restrict__ W0,
    const float* __restrict__ W1, const float* __restrict__ sc,
    const int* __restrict__ order, float* __restrict__ out, int N, int NPAD) {
  const int t = threadIdx.x;
  const int p = blockIdx.x * BLK + t;
  const int c1b = blockIdx.y * 8;             // block-uniform
  const int dd = blockIdx.z;                  // 0..3, block-uniform
  const int pc = (p < N) ? p : (N - 1);

  __shared__ float SR[BLK * 12];

  // A plane for this dd, packed quads: float4 at ((dd*32+cq)*NPAD+p)*4
  const float* Ap = tmp + ((size_t)(dd * 32) * NPAD + pc) * 4;
  const float* Wb = ((dd == 0) ? W0 : W1) + c1b;  // block-uniform -> s_load

  float acc[8];
#pragma unroll
  for (int k = 0; k < 8; ++k) acc[k] = 0.f;

#pragma unroll 4
  for (int cq = 0; cq < 32; ++cq) {
    const float4 a4 = *(const float4*)(Ap + (size_t)cq * NPAD * 4);
    const float* wr = Wb + cq * 4 * CCH;      // 4 rows; s_loads batch
#pragma unroll
    for (int k = 0; k < 8; ++k) acc[k] = fmaf(a4.x, wr[0 * CCH + k], acc[k]);
#pragma unroll
    for (int k = 0; k < 8; ++k) acc[k] = fmaf(a4.y, wr[1 * CCH + k], acc[k]);
#pragma unroll
    for (int k = 0; k < 8; ++k) acc[k] = fmaf(a4.z, wr[2 * CCH + k], acc[k]);
#pragma unroll
    for (int k = 0; k < 8; ++k) acc[k] = fmaf(a4.w, wr[3 * CCH + k], acc[k]);
  }

  const float s = 0.08838834764831843f;       // 1/sqrt(128)
#pragma unroll
  for (int k = 0; k < 8; ++k) SR[t * 12 + k] = acc[k] * s;
  __syncthreads();

  if (dd == 0) {
    // flush: 256 nodes x 2 float4 (8 cols), + sc residual
#pragma unroll
    for (int k = 0; k < 2; ++k) {
      const int idx = t + k * BLK;
      const int node = idx >> 1, f = idx & 1;
      const int p2 = blockIdx.x * BLK + node;
      if (p2 < N) {
        const int n = order[p2];
        const int gcol = c1b + f * 4;
        float4 v;
        v.x = SR[node * 12 + f * 4 + 0];
        v.y = SR[node * 12 + f * 4 + 1];
        v.z = SR[node * 12 + f * 4 + 2];
        v.w = SR[node * 12 + f * 4 + 3];
        const float4 sv = *(const float4*)(sc + (size_t)n * 512 + gcol);
        v.x += sv.x; v.y += sv.y; v.z += sv.z; v.w += sv.w;
        *(float4*)(out + (size_t)n * 512 + gcol) = v;
      }
    }
  } else {
    // flush: 8 rounds x (32 nodes x 8 stride-3 dwords), + sc residual
    const int jj = t & 7;                     // col within group
    const int nb0 = t >> 3;                   // node sub-index 0..31
#pragma unroll 1
    for (int nb = 0; nb < 8; ++nb) {
      const int node = nb0 + nb * 32;
      const int p2 = blockIdx.x * BLK + node;
      if (p2 < N) {
        const int n = order[p2];
        const int gcol = CCH + 3 * (c1b + jj) + (dd - 1);
        const float v = SR[node * 12 + jj];
        out[(size_t)n * 512 + gcol] = v + sc[(size_t)n * 512 + gcol];
      }
    }
  }
}

// -------------------------------------------------------------------- launch
extern "C" void kernel_launch(void* const* d_in, const int* in_sizes, int n_in,
                              void* d_out, int out_size, void* d_ws, size_t ws_size,
                              hipStream_t stream) {
  const float* feats = (const float*)d_in[0];
  const float* attrs = (const float*)d_in[1];
  const float* sc    = (const float*)d_in[2];
  const float* U3_0  = (const float*)d_in[3];
  const float* U2_0  = (const float*)d_in[4];
  const float* U1_0  = (const float*)d_in[5];
  const float* w3_0  = (const float*)d_in[6];
  const float* w2_0  = (const float*)d_in[7];
  const float* w1_0  = (const float*)d_in[8];
  const float* U3_1  = (const float*)d_in[9];
  const float* U2_1  = (const float*)d_in[10];
  const float* U1_1  = (const float*)d_in[11];
  const float* w3_1  = (const float*)d_in[12];
  const float* w2_1  = (const float*)d_in[13];
  const float* w1_1  = (const float*)d_in[14];
  const float* W0    = (const float*)d_in[15];
  const float* W1    = (const float*)d_in[16];

  const int N = in_sizes[0] / (CCH * LDIM);     // 10000
  const int NPAD = ((N + 15) & ~15) + 16;       // 10016

  // ws (floats): table[5*128*TGSTR] | tmp[4*32][NPAD][4] | order elem offs cur gcnt
  float* table = (float*)d_ws;
  float* tmp   = table + (size_t)NE * CCH * TGSTR;
  int*   order = (int*)(tmp + (size_t)4 * CCH * NPAD);
  int*   elem  = order + N;
  int*   offs  = elem + N;
  int*   cur   = offs + 8;
  int*   gcnt  = cur + 8;                       // gcnt[0..4], gcnt[5]=done
  float* out   = (float*)d_out;

  hipMemsetAsync(gcnt, 0, 8 * sizeof(int), stream);

  const int nblk = (N + BLK - 1) / BLK;
  count_offs_kernel<<<dim3(nblk), dim3(BLK), 0, stream>>>(
      attrs, N, elem, gcnt, offs, cur);
  scatter_kernel<<<dim3(nblk), dim3(BLK), 0, stream>>>(elem, N, cur, order);

  table_kernel<<<dim3(NE * CCH, 4), dim3(BLK), 0, stream>>>(
      U3_0, U2_0, U1_0, U3_1, U2_1, U1_1,
      w3_0, w2_0, w1_0, w3_1, w2_1, w1_1, table);

  // compact chunk grid: sum over e of ceil(cnt_e/BLK) <= N/BLK + NE
  const int chunksMax = (N + BLK - 1) / BLK + NE;
  contract_kernel<<<dim3(CCH, chunksMax), dim3(BLK), 0, stream>>>(
      feats, table, order, offs, tmp, NPAD);

  const int nchunk = (N + BLK - 1) / BLK;       // 40 (== 0 mod 8)
  linear_kernel<<<dim3(nchunk, 16, 4), dim3(BLK), 0, stream>>>(
      tmp, W0, W1, sc, order, out, N, NPAD);
}